// Round 7
// baseline (1125.782 us; speedup 1.0000x reference)
//
#include <hip/hip_runtime.h>
#include <cstdint>
#include <cstddef>

typedef __bf16 bf16;
typedef __bf16 bf16x4 __attribute__((ext_vector_type(4)));
typedef __bf16 bf16x8 __attribute__((ext_vector_type(8)));
typedef float  f32x4  __attribute__((ext_vector_type(4)));

#define LDS_CAST(p) ((__attribute__((address_space(3))) void*)(p))
#define GLB_CAST(p) ((const __attribute__((address_space(1))) void*)(p))

__device__ __forceinline__ void glds16(const void* g, void* l) {
  // 16B per lane, LDS dst = wave-uniform base + lane*16
  __builtin_amdgcn_global_load_lds(GLB_CAST(g), LDS_CAST(l), 16, 0, 0);
}

// ---------------------------------------------------------------------------
// Transpose-convert (all 6 layers, grid.z = layer): w fp32 [K,N] -> wt bf16 [N,K]
// ---------------------------------------------------------------------------
__global__ __launch_bounds__(256)
void convT_k(const float* __restrict__ w, bf16* __restrict__ wt, int K, int N)
{
  __shared__ bf16 t[64][72];
  const int tid = threadIdx.x;
  const int k0 = blockIdx.x * 64, n0 = blockIdx.y * 64;
  w  += (size_t)blockIdx.z * K * N;
  wt += (size_t)blockIdx.z * K * N;
  const int r = tid >> 4, c = (tid & 15) * 4;
#pragma unroll
  for (int p = 0; p < 4; ++p) {
    const int k = p * 16 + r;
    f32x4 v = *(const f32x4*)&w[(size_t)(k0 + k) * N + n0 + c];
    bf16x4 b = { (bf16)v[0], (bf16)v[1], (bf16)v[2], (bf16)v[3] };
    *(bf16x4*)&t[k][c] = b;
  }
  __syncthreads();
#pragma unroll
  for (int p = 0; p < 4; ++p) {
    const int n = p * 16 + r;
    bf16x4 b = { t[c + 0][n], t[c + 1][n], t[c + 2][n], t[c + 3][n] };
    *(bf16x4*)&wt[(size_t)(n0 + n) * K + k0 + c] = b;
  }
}

// ---------------------------------------------------------------------------
// Main GEMM: 128x128 tile, 4 waves (256 thr) as 2x2 of 64x64, ring-3 LDS
// (48 KB) -> 3 blocks/CU (12 waves/CU = m97 occupancy, the proven TLP
// regime), depth-2 prefetch, counted vmcnt(4) + RAW s_barrier (no drain).
// blockIdx.z = K-chunk (split-K): kBase = z*Kchunk, row stride ldK.
// EPI 0: bf16 store  EPI 2: +bias,exact GELU,bf16  EPI 3: fp32 partials.
// Staging: 16 units of 16 rows x 64B/step; wave w stages A units {w,w+4},
// B units {w,w+4} (4 glds16/wave/step). Per-lane global k pre-swizzled
// (verified involution: 16B slot s of row r holds k-block s ^ ((r>>1)&3));
// fragment reads apply the same XOR -> conflict-free ds_read_b128.
// T1: bijective chunked XCD swizzle on (x,y) (nwg_xy % 8 == 0 everywhere).
// ---------------------------------------------------------------------------
template<int EPI>
__global__ __launch_bounds__(256, 3)
void gemm3r_k(const bf16* __restrict__ A, const bf16* __restrict__ Bt,
              const float* __restrict__ bias, bf16* __restrict__ outB,
              float* __restrict__ outP,
              int M, int N, int ldK, int Kchunk)
{
  __shared__ bf16 stage[3][8192];   // ring: [buf][A 128x32 (4096 el) | B 128x32]

  const int tid  = threadIdx.x;
  const int wave = tid >> 6, lane = tid & 63;

  // T1 chunked XCD swizzle (x,y only; z is the K-chunk)
  const int nwg = gridDim.x * gridDim.y;
  int flat = blockIdx.y * gridDim.x + blockIdx.x;
  flat = (flat & 7) * (nwg >> 3) + (flat >> 3);
  const int bx = flat % gridDim.x, by = flat / gridDim.x;

  const int row0 = bx * 128, col0 = by * 128;
  const int wr = wave >> 1, wc = wave & 1;   // wave's 64x64 sub-tile
  const int kBase = blockIdx.z * Kchunk;

  // staging sources: 4 units/wave (A rows w*16.., A rows 64+w*16.., B same)
  const int srow = lane >> 2;                              // row within 16-chunk
  const int ssw  = ((lane & 3) ^ ((lane >> 3) & 3)) << 3;  // swizzled k elems
  const bf16* srcA0 = A  + (size_t)(row0 + wave * 16 + srow) * ldK + kBase + ssw;
  const bf16* srcA1 = A  + (size_t)(row0 + 64 + wave * 16 + srow) * ldK + kBase + ssw;
  const bf16* srcB0 = Bt + (size_t)(col0 + wave * 16 + srow) * ldK + kBase + ssw;
  const bf16* srcB1 = Bt + (size_t)(col0 + 64 + wave * 16 + srow) * ldK + kBase + ssw;
  const int dA0 = wave * 512, dA1 = (wave + 4) * 512;
  const int dB0 = 4096 + wave * 512, dB1 = 4096 + (wave + 4) * 512;

  // fragment reads: slot = q ^ ((row>>1)&3); unit-relative row keeps key = (fr>>1)&3
  const int fr  = lane & 15;
  const int fq8 = (((lane >> 4) ^ ((fr >> 1) & 3))) << 3;

  f32x4 acc[4][4] = {};

#define STAGE3(bufp, kt)                                                       \
  {                                                                            \
    const int k0_ = (kt) << 5;                                                 \
    glds16(srcA0 + k0_, (bufp) + dA0);                                         \
    glds16(srcA1 + k0_, (bufp) + dA1);                                         \
    glds16(srcB0 + k0_, (bufp) + dB0);                                         \
    glds16(srcB1 + k0_, (bufp) + dB1);                                         \
  }

#define COMPUTE3(bufp)                                                         \
  {                                                                            \
    const bf16* sb_ = (bufp);                                                  \
    bf16x8 af[4], bfr[4];                                                      \
    _Pragma("unroll")                                                          \
    for (int t_ = 0; t_ < 4; ++t_) {                                           \
      af[t_]  = *(const bf16x8*)&sb_[(wr * 64 + t_ * 16 + fr) * 32 + fq8];     \
      bfr[t_] = *(const bf16x8*)&sb_[4096 + (wc * 64 + t_ * 16 + fr) * 32 + fq8]; \
    }                                                                          \
    __builtin_amdgcn_s_setprio(1);                                             \
    _Pragma("unroll")                                                          \
    for (int i_ = 0; i_ < 4; ++i_)                                             \
      _Pragma("unroll")                                                        \
      for (int j_ = 0; j_ < 4; ++j_)                                           \
        acc[i_][j_] = __builtin_amdgcn_mfma_f32_16x16x32_bf16(                 \
            af[i_], bfr[j_], acc[i_][j_], 0, 0, 0);                            \
    __builtin_amdgcn_s_setprio(0);                                             \
  }

#define WAITB(n)                                                               \
  asm volatile("s_waitcnt vmcnt(" #n ")" ::: "memory");                        \
  __builtin_amdgcn_s_barrier();                                                \
  __builtin_amdgcn_sched_barrier(0);

  const int nk = Kchunk >> 5;            // >= 2
  bf16 *bA = stage[0], *bB = stage[1], *bC = stage[2];
  STAGE3(bA, 0);
  STAGE3(bB, 1);                         // 8 loads in flight / wave

  for (int kt = 0; kt < nk - 2; ++kt) {
    WAITB(4);                            // stage kt landed; kt+1 in flight
    STAGE3(bC, kt + 2);
    COMPUTE3(bA);
    bf16* t_ = bA; bA = bB; bB = bC; bC = t_;   // rotate ring
  }
  WAITB(4);  COMPUTE3(bA);
  WAITB(0);  COMPUTE3(bB);

#undef STAGE3
#undef COMPUTE3
#undef WAITB

  // per-wave epilogue (register acc, disjoint outputs)
#pragma unroll
  for (int i = 0; i < 4; ++i) {
    const int rb = row0 + wr * 64 + i * 16 + (lane >> 4) * 4;
#pragma unroll
    for (int j = 0; j < 4; ++j) {
      const int c = col0 + wc * 64 + j * 16 + fr;
      const float bv = (EPI == 2) ? bias[c] : 0.f;
#pragma unroll
      for (int r = 0; r < 4; ++r) {
        float v = acc[i][j][r] + bv;
        if (EPI == 3) {
          outP[(size_t)blockIdx.z * M * N + (size_t)(rb + r) * N + c] = v;
        } else {
          if (EPI == 2) v = 0.5f * v * (1.f + erff(v * 0.70710678118654752f));
          outB[(size_t)(rb + r) * N + c] = (bf16)v;
        }
      }
    }
  }
}

// ---------------------------------------------------------------------------
// Split-K reduce for ff2 (+ optional fused LayerNorm of the result row).
// out = P0+P1+P2+P3 + bias + resid (fp32; out may alias resid).
// LN==1: additionally write bf16 LN(out) row to lnout (next layer's ln1).
// Grid = M blocks (one row each), 256 thr x f32x4 = N=1024.
// ---------------------------------------------------------------------------
template<int LN>
__global__ __launch_bounds__(256)
void red4_k(const float* __restrict__ P, const float* __restrict__ bias,
            const float* resid, float* outF,
            const float* __restrict__ sc, const float* __restrict__ bi,
            bf16* __restrict__ lnout, int M, int N)
{
  const int row = blockIdx.x, tid = threadIdx.x, c = tid * 4;
  const size_t MN = (size_t)M * N;
  const size_t idx = (size_t)row * N + c;
  f32x4 p0 = *(const f32x4*)&P[idx];
  f32x4 p1 = *(const f32x4*)&P[MN + idx];
  f32x4 p2 = *(const f32x4*)&P[2 * MN + idx];
  f32x4 p3 = *(const f32x4*)&P[3 * MN + idx];
  f32x4 bv = *(const f32x4*)&bias[c];
  f32x4 rv = *(const f32x4*)&resid[idx];
  f32x4 o;
#pragma unroll
  for (int e = 0; e < 4; ++e) o[e] = p0[e] + p1[e] + p2[e] + p3[e] + bv[e] + rv[e];
  *(f32x4*)&outF[idx] = o;

  if (LN) {
    float s  = o[0] + o[1] + o[2] + o[3];
    float s2 = o[0]*o[0] + o[1]*o[1] + o[2]*o[2] + o[3]*o[3];
#pragma unroll
    for (int m = 32; m >= 1; m >>= 1) {
      s  += __shfl_xor(s, m);
      s2 += __shfl_xor(s2, m);
    }
    __shared__ float red[8];
    if ((tid & 63) == 0) { red[tid >> 6] = s; red[4 + (tid >> 6)] = s2; }
    __syncthreads();
    s  = red[0] + red[1] + red[2] + red[3];
    s2 = red[4] + red[5] + red[6] + red[7];
    const float mean = s * (1.f / 1024.f);
    const float var  = s2 * (1.f / 1024.f) - mean * mean;
    const float rs   = rsqrtf(var + 1e-5f);
    bf16x4 ov;
#pragma unroll
    for (int e = 0; e < 4; ++e)
      ov[e] = (bf16)((o[e] - mean) * rs * sc[c + e] + bi[c + e]);
    *(bf16x4*)&lnout[idx] = ov;
  }
}

// ---------------------------------------------------------------------------
// wout GEMM (N=1024, K=1024): barrier-free per-wave split-K.
// [harness-verified in round 1 -- unchanged]
// ---------------------------------------------------------------------------
__global__ __launch_bounds__(256, 2)
void gemm64s_k(const bf16* __restrict__ A, const bf16* __restrict__ Bt,
               const float* __restrict__ bias, const float* resid,
               float* outF, int M, int N, int K)
{
  union SMem {
    bf16  stage[4][2][2][2048];   // [wave][buf][A=0/B=1][64*32] = 64 KiB
    float red[4][64 * 68];        // 69632 B (padded stride 68)
  };
  __shared__ SMem sm;

  const int tid  = threadIdx.x;
  const int wave = tid >> 6, lane = tid & 63;
  const int row0 = blockIdx.x * 64, col0 = blockIdx.y * 64;
  const int kChunk = K >> 2;
  const int nk = kChunk >> 5;               // 32-wide K-steps per wave

  const int srow = lane >> 2;                              // row within 16-chunk
  const int ssw  = ((lane & 3) ^ ((lane >> 3) & 3)) << 3;  // swizzled k elems
  const bf16* Ab = A  + (size_t)(row0 + srow) * K + wave * kChunk + ssw;
  const bf16* Bb = Bt + (size_t)(col0 + srow) * K + wave * kChunk + ssw;

  const int fr  = lane & 15;
  const int fq8 = (((lane >> 4) ^ ((fr >> 1) & 3))) << 3;

  f32x4 acc[4][4] = {};

#define STAGE(buf, kt)                                                         \
  {                                                                            \
    const int k0_ = (kt) << 5;                                                 \
    bf16* pa_ = sm.stage[wave][buf][0];                                        \
    bf16* pb_ = sm.stage[wave][buf][1];                                        \
    _Pragma("unroll")                                                          \
    for (int c_ = 0; c_ < 4; ++c_) {                                           \
      glds16(Ab + (size_t)c_ * 16 * K + k0_, pa_ + c_ * 512);                  \
      glds16(Bb + (size_t)c_ * 16 * K + k0_, pb_ + c_ * 512);                  \
    }                                                                          \
  }

#define COMPUTE(buf)                                                           \
  {                                                                            \
    const bf16* pa_ = sm.stage[wave][buf][0];                                  \
    const bf16* pb_ = sm.stage[wave][buf][1];                                  \
    bf16x8 af[4], bfr[4];                                                      \
    _Pragma("unroll")                                                          \
    for (int t_ = 0; t_ < 4; ++t_) {                                           \
      af[t_]  = *(const bf16x8*)(pa_ + (t_ * 16 + fr) * 32 + fq8);             \
      bfr[t_] = *(const bf16x8*)(pb_ + (t_ * 16 + fr) * 32 + fq8);             \
    }                                                                          \
    __builtin_amdgcn_s_setprio(1);                                             \
    _Pragma("unroll")                                                          \
    for (int i_ = 0; i_ < 4; ++i_)                                             \
      _Pragma("unroll")                                                        \
      for (int j_ = 0; j_ < 4; ++j_)                                           \
        acc[i_][j_] = __builtin_amdgcn_mfma_f32_16x16x32_bf16(                 \
            af[i_], bfr[j_], acc[i_][j_], 0, 0, 0);                            \
    __builtin_amdgcn_s_setprio(0);                                             \
  }

  STAGE(0, 0);
  for (int kt = 0; kt < nk - 1; ++kt) {
    STAGE((kt + 1) & 1, kt + 1);                       // 16 outstanding
    asm volatile("s_waitcnt vmcnt(8)" ::: "memory");   // oldest 8 = cur tile
    COMPUTE(kt & 1);
  }
  asm volatile("s_waitcnt vmcnt(0)" ::: "memory");
  COMPUTE((nk - 1) & 1);

#undef STAGE
#undef COMPUTE

  // ---- cross-wave reduction (LDS reused; must fence all waves first) ----
  __syncthreads();
#pragma unroll
  for (int i = 0; i < 4; ++i)
#pragma unroll
    for (int j = 0; j < 4; ++j)
#pragma unroll
      for (int r = 0; r < 4; ++r)
        sm.red[wave][(i * 16 + ((lane >> 4) << 2) + r) * 68 + j * 16 + (lane & 15)] =
            acc[i][j][r];
  __syncthreads();

  const int er = tid >> 2;              // row 0..63
  const int ec = (tid & 3) << 2;        // col quarter-base (stride 16 via v)
  const size_t gbase = (size_t)(row0 + er) * N + col0 + ec;
#pragma unroll
  for (int v = 0; v < 4; ++v) {
    const int lo = er * 68 + ec + v * 16;
    f32x4 s0 = *(const f32x4*)&sm.red[0][lo];
    f32x4 s1 = *(const f32x4*)&sm.red[1][lo];
    f32x4 s2 = *(const f32x4*)&sm.red[2][lo];
    f32x4 s3 = *(const f32x4*)&sm.red[3][lo];
    f32x4 bv = *(const f32x4*)&bias[col0 + ec + v * 16];
    f32x4 rv = *(const f32x4*)&resid[gbase + v * 16];
    f32x4 o;
#pragma unroll
    for (int e = 0; e < 4; ++e) o[e] = s0[e] + s1[e] + s2[e] + s3[e] + bv[e] + rv[e];
    *(f32x4*)&outF[gbase + v * 16] = o;
  }
}

// ---------------------------------------------------------------------------
// Attention: qkv bf16 [B*N, 3072] -> o bf16 [B*N, 1024] (col = h*64+d)
// grid (B*H=64, N/128=4), 512 threads (8 waves, 16 q-rows each).
// ---------------------------------------------------------------------------
__global__ __launch_bounds__(512, 2)
void attn_k(const bf16* __restrict__ qkv, bf16* __restrict__ o)
{
  __shared__ bf16 Ks[512 * 72];     // [j][d], stride 72
  __shared__ bf16 Vt[64 * 520];     // [d][j], stride 520
  __shared__ bf16 Pl[8][16 * 72];   // per-wave P chunk [i][j_local], 64 cols

  const int tid = threadIdx.x, wave = tid >> 6, lane = tid & 63;
  const int b = blockIdx.x >> 4, h = blockIdx.x & 15;
  const int i0g = blockIdx.y * 128 + wave * 16;
  const bf16* base = qkv + (size_t)b * 512 * 3072;

  { // K -> LDS row-major
    const int jr = tid >> 3, c0 = (tid & 7) * 8;
#pragma unroll
    for (int p = 0; p < 8; ++p) {
      const int j = p * 64 + jr;
      *(bf16x8*)&Ks[j * 72 + c0] =
          *(const bf16x8*)&base[(size_t)j * 3072 + 1024 + h * 64 + c0];
    }
  }
  { // V -> LDS transposed
    const int jr = tid >> 4, d0 = (tid & 15) * 4;
#pragma unroll
    for (int p = 0; p < 16; ++p) {
      const int j = p * 32 + jr;
      bf16x4 v = *(const bf16x4*)&base[(size_t)j * 3072 + 2048 + h * 64 + d0];
      Vt[(d0 + 0) * 520 + j] = v[0];
      Vt[(d0 + 1) * 520 + j] = v[1];
      Vt[(d0 + 2) * 520 + j] = v[2];
      Vt[(d0 + 3) * 520 + j] = v[3];
    }
  }
  bf16x8 qf[2];
  {
    const int qr = i0g + (lane & 15);
#pragma unroll
    for (int t = 0; t < 2; ++t)
      qf[t] = *(const bf16x8*)&base[(size_t)qr * 3072 + h * 64 + t * 32 + (lane >> 4) * 8];
  }
  __syncthreads();

  // S = Q K^T : each wave 16 rows x 512 cols (32 n-tiles, 2 k-steps of 32)
  f32x4 S[32];
#pragma unroll
  for (int nt = 0; nt < 32; ++nt) {
    const bf16* kb = &Ks[(nt * 16 + (lane & 15)) * 72 + (lane >> 4) * 8];
    f32x4 c = {};
    c = __builtin_amdgcn_mfma_f32_16x16x32_bf16(qf[0], *(const bf16x8*)kb, c, 0, 0, 0);
    c = __builtin_amdgcn_mfma_f32_16x16x32_bf16(qf[1], *(const bf16x8*)(kb + 32), c, 0, 0, 0);
    S[nt] = c;
  }

  // softmax over rows (C-layout: row=(lane>>4)*4+r, col=nt*16+(lane&15))
  float mx[4] = {-1e30f, -1e30f, -1e30f, -1e30f};
#pragma unroll
  for (int nt = 0; nt < 32; ++nt)
#pragma unroll
    for (int r = 0; r < 4; ++r) {
      S[nt][r] *= 0.125f;
      mx[r] = fmaxf(mx[r], S[nt][r]);
    }
#pragma unroll
  for (int m = 1; m < 16; m <<= 1)
#pragma unroll
    for (int r = 0; r < 4; ++r) mx[r] = fmaxf(mx[r], __shfl_xor(mx[r], m));
  float sm[4] = {0.f, 0.f, 0.f, 0.f};
#pragma unroll
  for (int nt = 0; nt < 32; ++nt)
#pragma unroll
    for (int r = 0; r < 4; ++r) {
      const float e = __expf(S[nt][r] - mx[r]);
      S[nt][r] = e;
      sm[r] += e;
    }
#pragma unroll
  for (int m = 1; m < 16; m <<= 1)
#pragma unroll
    for (int r = 0; r < 4; ++r) sm[r] += __shfl_xor(sm[r], m);
  float inv[4];
#pragma unroll
  for (int r = 0; r < 4; ++r) inv[r] = 1.f / sm[r];

  // O = P V: P roundtrips per-wave LDS (C-layout -> A-layout), 8 chunks of 64
  f32x4 O[4] = {};
  for (int cch = 0; cch < 8; ++cch) {
#pragma unroll
    for (int t = 0; t < 4; ++t) {
      const int nt = cch * 4 + t;
#pragma unroll
      for (int r = 0; r < 4; ++r)
        Pl[wave][((lane >> 4) * 4 + r) * 72 + t * 16 + (lane & 15)] = (bf16)S[nt][r];
    }
#pragma unroll
    for (int ktile = 0; ktile < 2; ++ktile) {
      bf16x8 pf = *(const bf16x8*)&Pl[wave][(lane & 15) * 72 + ktile * 32 + (lane >> 4) * 8];
#pragma unroll
      for (int dt = 0; dt < 4; ++dt) {
        const bf16* vb = &Vt[(dt * 16 + (lane & 15)) * 520 + cch * 64 + ktile * 32 + (lane >> 4) * 8];
        O[dt] = __builtin_amdgcn_mfma_f32_16x16x32_bf16(pf, *(const bf16x8*)vb, O[dt], 0, 0, 0);
      }
    }
  }

#pragma unroll
  for (int dt = 0; dt < 4; ++dt)
#pragma unroll
    for (int r = 0; r < 4; ++r) {
      const int i = (lane >> 4) * 4 + r;
      const int d = dt * 16 + (lane & 15);
      o[(size_t)(b * 512 + i0g + i) * 1024 + h * 64 + d] = (bf16)(O[dt][r] * inv[r]);
    }
}

// ---------------------------------------------------------------------------
// LayerNorm: x fp32 [rows,1024], fp32 scale/bias -> bf16 out
// ---------------------------------------------------------------------------
__global__ __launch_bounds__(256)
void ln_k(const float* __restrict__ x, const float* __restrict__ sc,
          const float* __restrict__ bi, bf16* __restrict__ out)
{
  const int row = blockIdx.x, tid = threadIdx.x;
  f32x4 a = *(const f32x4*)&x[(size_t)row * 1024 + tid * 4];
  float s  = a[0] + a[1] + a[2] + a[3];
  float s2 = a[0]*a[0] + a[1]*a[1] + a[2]*a[2] + a[3]*a[3];
#pragma unroll
  for (int m = 32; m >= 1; m >>= 1) {
    s  += __shfl_xor(s, m);
    s2 += __shfl_xor(s2, m);
  }
  __shared__ float red[8];
  if ((tid & 63) == 0) { red[tid >> 6] = s; red[4 + (tid >> 6)] = s2; }
  __syncthreads();
  s  = red[0] + red[1] + red[2] + red[3];
  s2 = red[4] + red[5] + red[6] + red[7];
  const float mean = s * (1.f / 1024.f);
  const float var  = s2 * (1.f / 1024.f) - mean * mean;
  const float rs   = rsqrtf(var + 1e-5f);
  bf16x4 ov;
#pragma unroll
  for (int i = 0; i < 4; ++i) {
    const int c = tid * 4 + i;
    ov[i] = (bf16)((a[i] - mean) * rs * sc[c] + bi[c]);
  }
  *(bf16x4*)&out[(size_t)row * 1024 + tid * 4] = ov;
}

// ---------------------------------------------------------------------------
extern "C" void kernel_launch(void* const* d_in, const int* in_sizes, int n_in,
                              void* d_out, int out_size, void* d_ws, size_t ws_size,
                              hipStream_t stream)
{
  const float* x_in = (const float*)d_in[0];
  const float* ln1s = (const float*)d_in[1];
  const float* ln1b = (const float*)d_in[2];
  const float* wqkv = (const float*)d_in[3];
  const float* wout = (const float*)d_in[4];
  const float* bout = (const float*)d_in[5];
  const float* ln2s = (const float*)d_in[6];
  const float* ln2b = (const float*)d_in[7];
  const float* w1   = (const float*)d_in[8];
  const float* b1   = (const float*)d_in[9];
  const float* w2   = (const float*)d_in[10];
  const float* b2   = (const float*)d_in[11];

  char* ws = (char*)d_ws;
  const size_t MB = 1 << 20;
  float* xf   = (float*)(ws);              // 8 MiB fp32 residual stream
  bf16* act   = (bf16*)(ws + 8   * MB);    // 4 MiB: ln out / attn out
  bf16* qg    = (bf16*)(ws + 12  * MB);    // 16 MiB: qkv (12) then gelu (16)
  bf16* qkvT  = (bf16*)(ws + 28  * MB);    // 36 MiB [6][3072,1024]
  bf16* woutT = (bf16*)(ws + 64  * MB);    // 12 MiB [6][1024,1024]
  bf16* w1T   = (bf16*)(ws + 76  * MB);    // 48 MiB [6][4096,1024]
  bf16* w2T   = (bf16*)(ws + 124 * MB);    // 48 MiB [6][1024,4096]
  float* Pws  = (float*)(ws + 172 * MB);   // 32 MiB [4][2048,1024] fp32 partials

  // transpose-convert all layers' weights to bf16 [N,K]
  convT_k<<<dim3(16, 48, 6), 256, 0, stream>>>(wqkv, qkvT, 1024, 3072);
  convT_k<<<dim3(16, 16, 6), 256, 0, stream>>>(wout, woutT, 1024, 1024);
  convT_k<<<dim3(16, 64, 6), 256, 0, stream>>>(w1, w1T, 1024, 4096);
  convT_k<<<dim3(64, 16, 6), 256, 0, stream>>>(w2, w2T, 4096, 1024);

  for (int l = 0; l < 6; ++l) {
    const float* xres = (l == 0) ? x_in : xf;  // residual-stream input
    if (l == 0)  // ln1 for l>0 is fused into the previous layer's red4_k<1>
      ln_k<<<2048, 256, 0, stream>>>(x_in, ln1s, ln1b, act);
    gemm3r_k<0><<<dim3(16, 24, 1), 256, 0, stream>>>(
        act, qkvT + (size_t)l * 3072 * 1024, nullptr, qg, nullptr,
        2048, 3072, 1024, 1024);
    attn_k<<<dim3(64, 4), 512, 0, stream>>>(qg, act);
    gemm64s_k<<<dim3(32, 16), 256, 0, stream>>>(
        act, woutT + (size_t)l * 1024 * 1024, bout + l * 1024, xres, xf,
        2048, 1024, 1024);
    ln_k<<<2048, 256, 0, stream>>>(xf, ln2s + l * 1024, ln2b + l * 1024, act);
    gemm3r_k<2><<<dim3(16, 32, 1), 256, 0, stream>>>(
        act, w1T + (size_t)l * 4096 * 1024, b1 + l * 4096, qg, nullptr,
        2048, 4096, 1024, 1024);
    // ff2: split-K x4 on the ring structure, then fused reduce (+ next ln1)
    gemm3r_k<3><<<dim3(16, 8, 4), 256, 0, stream>>>(
        qg, w2T + (size_t)l * 1024 * 4096, nullptr, nullptr, Pws,
        2048, 1024, 4096, 1024);
    if (l < 5) {
      red4_k<1><<<2048, 256, 0, stream>>>(
          Pws, b2 + l * 1024, xf, xf,
          ln1s + (l + 1) * 1024, ln1b + (l + 1) * 1024, act, 2048, 1024);
    } else {
      red4_k<0><<<2048, 256, 0, stream>>>(
          Pws, b2 + l * 1024, xf, (float*)d_out,
          nullptr, nullptr, nullptr, 2048, 1024);
    }
  }
}

// Round 8
// 1085.774 us; speedup vs baseline: 1.0368x; 1.0368x over previous
//
#include <hip/hip_runtime.h>
#include <cstdint>
#include <cstddef>

typedef __bf16 bf16;
typedef __bf16 bf16x4 __attribute__((ext_vector_type(4)));
typedef __bf16 bf16x8 __attribute__((ext_vector_type(8)));
typedef float  f32x4  __attribute__((ext_vector_type(4)));

#define LDS_CAST(p) ((__attribute__((address_space(3))) void*)(p))
#define GLB_CAST(p) ((const __attribute__((address_space(1))) void*)(p))

__device__ __forceinline__ void glds16(const void* g, void* l) {
  // 16B per lane, LDS dst = wave-uniform base + lane*16
  __builtin_amdgcn_global_load_lds(GLB_CAST(g), LDS_CAST(l), 16, 0, 0);
}

// ---------------------------------------------------------------------------
// Transpose-convert (all 6 layers, grid.z = layer): w fp32 [K,N] -> wt bf16 [N,K]
// ---------------------------------------------------------------------------
__global__ __launch_bounds__(256)
void convT_k(const float* __restrict__ w, bf16* __restrict__ wt, int K, int N)
{
  __shared__ bf16 t[64][72];
  const int tid = threadIdx.x;
  const int k0 = blockIdx.x * 64, n0 = blockIdx.y * 64;
  w  += (size_t)blockIdx.z * K * N;
  wt += (size_t)blockIdx.z * K * N;
  const int r = tid >> 4, c = (tid & 15) * 4;
#pragma unroll
  for (int p = 0; p < 4; ++p) {
    const int k = p * 16 + r;
    f32x4 v = *(const f32x4*)&w[(size_t)(k0 + k) * N + n0 + c];
    bf16x4 b = { (bf16)v[0], (bf16)v[1], (bf16)v[2], (bf16)v[3] };
    *(bf16x4*)&t[k][c] = b;
  }
  __syncthreads();
#pragma unroll
  for (int p = 0; p < 4; ++p) {
    const int n = p * 16 + r;
    bf16x4 b = { t[c + 0][n], t[c + 1][n], t[c + 2][n], t[c + 3][n] };
    *(bf16x4*)&wt[(size_t)(n0 + n) * K + k0 + c] = b;
  }
}

// ---------------------------------------------------------------------------
// Deep-ring GEMM [exact R6 code -- best measured]: SHARED 128x256 tile,
// 8 waves as 2x4 of 64x64, 6-buffer LDS ring (144 KB), 5-K-steps-ahead
// prefetch, counted vmcnt(12) in the loop (never drain to 0), RAW s_barrier
// (no implicit vmcnt drain). Tail drains 12/9/6/3/0.
// blockIdx.z = K-chunk (split-K): kBase = z*Kchunk, row stride ldK.
// EPI 0: bf16 store  EPI 2: +bias,exact GELU,bf16  EPI 3: fp32 partials.
// Staging: 24 units of 16 rows x 64B; wave w stages units {w, w+8, w+16};
// per-lane global k pre-swizzled (verified involution: 16B slot s of row r
// holds k-block s ^ ((r>>1)&3)); fragment reads apply the same XOR ->
// conflict-free ds_read_b128.
// T1: bijective chunked XCD swizzle on (x,y) (nwg_xy % 8 == 0 everywhere).
// ---------------------------------------------------------------------------
template<int EPI>
__global__ __launch_bounds__(512, 1)
void gemm4r_k(const bf16* __restrict__ A, const bf16* __restrict__ Bt,
              const float* __restrict__ bias, bf16* __restrict__ outB,
              float* __restrict__ outP,
              int M, int N, int ldK, int Kchunk)
{
  __shared__ bf16 stage[6][12288];   // ring: [buf][A 128x32 (4096) | B 256x32 (8192)]

  const int tid  = threadIdx.x;
  const int wave = tid >> 6, lane = tid & 63;

  // T1 chunked XCD swizzle (x,y only; z is the K-chunk)
  const int nwg = gridDim.x * gridDim.y;
  int flat = blockIdx.y * gridDim.x + blockIdx.x;
  flat = (flat & 7) * (nwg >> 3) + (flat >> 3);
  const int bx = flat % gridDim.x, by = flat / gridDim.x;

  const int row0 = bx * 128, col0 = by * 256;
  const int wr = wave >> 2, wc = wave & 3;   // wave's 64x64 sub-tile
  const int kBase = blockIdx.z * Kchunk;

  // staging sources (3 units/wave: A rows w*16.., B rows w*16.., B rows 128+w*16..)
  const int srow = lane >> 2;                              // row within 16-chunk
  const int ssw  = ((lane & 3) ^ ((lane >> 3) & 3)) << 3;  // swizzled k elems
  const bf16* src0 = A  + (size_t)(row0 + wave * 16 + srow) * ldK + kBase + ssw;
  const bf16* src1 = Bt + (size_t)(col0 + wave * 16 + srow) * ldK + kBase + ssw;
  const bf16* src2 = Bt + (size_t)(col0 + 128 + wave * 16 + srow) * ldK + kBase + ssw;
  const int d0 = wave * 512;            // elem offsets of the 1KB units
  const int d1 = 4096 + wave * 512;
  const int d2 = 8192 + wave * 512;

  // fragment reads: slot = q ^ ((row>>1)&3); row = t*16+fr keeps it = (fr>>1)&3
  const int fr  = lane & 15;
  const int fq8 = (((lane >> 4) ^ ((fr >> 1) & 3))) << 3;

  f32x4 acc[4][4] = {};

#define STAGE6(buf, kt)                                                        \
  {                                                                            \
    const int k0_ = (kt) << 5;                                                 \
    glds16(src0 + k0_, &stage[buf][d0]);                                       \
    glds16(src1 + k0_, &stage[buf][d1]);                                       \
    glds16(src2 + k0_, &stage[buf][d2]);                                       \
  }

#define COMPUTE6(buf)                                                          \
  {                                                                            \
    const bf16* sb_ = stage[buf];                                              \
    bf16x8 af[4], bfr[4];                                                      \
    _Pragma("unroll")                                                          \
    for (int t_ = 0; t_ < 4; ++t_) {                                           \
      af[t_]  = *(const bf16x8*)&sb_[(wr * 64 + t_ * 16 + fr) * 32 + fq8];     \
      bfr[t_] = *(const bf16x8*)&sb_[4096 + (wc * 64 + t_ * 16 + fr) * 32 + fq8]; \
    }                                                                          \
    __builtin_amdgcn_s_setprio(1);                                             \
    _Pragma("unroll")                                                          \
    for (int i_ = 0; i_ < 4; ++i_)                                             \
      _Pragma("unroll")                                                        \
      for (int j_ = 0; j_ < 4; ++j_)                                           \
        acc[i_][j_] = __builtin_amdgcn_mfma_f32_16x16x32_bf16(                 \
            af[i_], bfr[j_], acc[i_][j_], 0, 0, 0);                            \
    __builtin_amdgcn_s_setprio(0);                                             \
  }

#define WAITB(n)                                                               \
  asm volatile("s_waitcnt vmcnt(" #n ")" ::: "memory");                        \
  __builtin_amdgcn_s_barrier();                                                \
  __builtin_amdgcn_sched_barrier(0);

  const int nk = Kchunk >> 5;            // >= 6 required (32 or 8 here)
  STAGE6(0, 0); STAGE6(1, 1); STAGE6(2, 2); STAGE6(3, 3); STAGE6(4, 4);

  for (int kt = 0; kt < nk - 5; ++kt) {
    WAITB(12);                           // own stage-kt landed; 4 stages in flight
    STAGE6((kt + 5) % 6, kt + 5);
    COMPUTE6(kt % 6);
  }
  WAITB(12); COMPUTE6((nk - 5) % 6);
  WAITB(9);  COMPUTE6((nk - 4) % 6);
  WAITB(6);  COMPUTE6((nk - 3) % 6);
  WAITB(3);  COMPUTE6((nk - 2) % 6);
  WAITB(0);  COMPUTE6((nk - 1) % 6);

#undef STAGE6
#undef COMPUTE6
#undef WAITB

  // per-wave epilogue (register acc, disjoint outputs)
#pragma unroll
  for (int i = 0; i < 4; ++i) {
    const int rb = row0 + wr * 64 + i * 16 + (lane >> 4) * 4;
#pragma unroll
    for (int j = 0; j < 4; ++j) {
      const int c = col0 + wc * 64 + j * 16 + fr;
      const float bv = (EPI == 2) ? bias[c] : 0.f;
#pragma unroll
      for (int r = 0; r < 4; ++r) {
        float v = acc[i][j][r] + bv;
        if (EPI == 3) {
          outP[(size_t)blockIdx.z * M * N + (size_t)(rb + r) * N + c] = v;
        } else {
          if (EPI == 2) v = 0.5f * v * (1.f + erff(v * 0.70710678118654752f));
          outB[(size_t)(rb + r) * N + c] = (bf16)v;
        }
      }
    }
  }
}

// ---------------------------------------------------------------------------
// Split-K reduce (+ optional fused LayerNorm of the result row).
// out = P0+P1+P2+P3 + bias + resid (fp32; out may alias resid).
// LN==1: additionally write bf16 LN(out) row to lnout.
// Used for: wout (+ln2 fused) and ff2 (+next layer's ln1 fused).
// Grid = M blocks (one row each), 256 thr x f32x4 = N=1024.
// [LN fusion harness-verified in round 7]
// ---------------------------------------------------------------------------
template<int LN>
__global__ __launch_bounds__(256)
void red4_k(const float* __restrict__ P, const float* __restrict__ bias,
            const float* resid, float* outF,
            const float* __restrict__ sc, const float* __restrict__ bi,
            bf16* __restrict__ lnout, int M, int N)
{
  const int row = blockIdx.x, tid = threadIdx.x, c = tid * 4;
  const size_t MN = (size_t)M * N;
  const size_t idx = (size_t)row * N + c;
  f32x4 p0 = *(const f32x4*)&P[idx];
  f32x4 p1 = *(const f32x4*)&P[MN + idx];
  f32x4 p2 = *(const f32x4*)&P[2 * MN + idx];
  f32x4 p3 = *(const f32x4*)&P[3 * MN + idx];
  f32x4 bv = *(const f32x4*)&bias[c];
  f32x4 rv = *(const f32x4*)&resid[idx];
  f32x4 o;
#pragma unroll
  for (int e = 0; e < 4; ++e) o[e] = p0[e] + p1[e] + p2[e] + p3[e] + bv[e] + rv[e];
  *(f32x4*)&outF[idx] = o;

  if (LN) {
    float s  = o[0] + o[1] + o[2] + o[3];
    float s2 = o[0]*o[0] + o[1]*o[1] + o[2]*o[2] + o[3]*o[3];
#pragma unroll
    for (int m = 32; m >= 1; m >>= 1) {
      s  += __shfl_xor(s, m);
      s2 += __shfl_xor(s2, m);
    }
    __shared__ float red[8];
    if ((tid & 63) == 0) { red[tid >> 6] = s; red[4 + (tid >> 6)] = s2; }
    __syncthreads();
    s  = red[0] + red[1] + red[2] + red[3];
    s2 = red[4] + red[5] + red[6] + red[7];
    const float mean = s * (1.f / 1024.f);
    const float var  = s2 * (1.f / 1024.f) - mean * mean;
    const float rs   = rsqrtf(var + 1e-5f);
    bf16x4 ov;
#pragma unroll
    for (int e = 0; e < 4; ++e)
      ov[e] = (bf16)((o[e] - mean) * rs * sc[c + e] + bi[c + e]);
    *(bf16x4*)&lnout[idx] = ov;
  }
}

// ---------------------------------------------------------------------------
// Attention: qkv bf16 [B*N, 3072] -> o bf16 [B*N, 1024] (col = h*64+d)
// grid (B*H=64, N/128=4), 512 threads (8 waves, 16 q-rows each).
// ---------------------------------------------------------------------------
__global__ __launch_bounds__(512, 2)
void attn_k(const bf16* __restrict__ qkv, bf16* __restrict__ o)
{
  __shared__ bf16 Ks[512 * 72];     // [j][d], stride 72
  __shared__ bf16 Vt[64 * 520];     // [d][j], stride 520
  __shared__ bf16 Pl[8][16 * 72];   // per-wave P chunk [i][j_local], 64 cols

  const int tid = threadIdx.x, wave = tid >> 6, lane = tid & 63;
  const int b = blockIdx.x >> 4, h = blockIdx.x & 15;
  const int i0g = blockIdx.y * 128 + wave * 16;
  const bf16* base = qkv + (size_t)b * 512 * 3072;

  { // K -> LDS row-major
    const int jr = tid >> 3, c0 = (tid & 7) * 8;
#pragma unroll
    for (int p = 0; p < 8; ++p) {
      const int j = p * 64 + jr;
      *(bf16x8*)&Ks[j * 72 + c0] =
          *(const bf16x8*)&base[(size_t)j * 3072 + 1024 + h * 64 + c0];
    }
  }
  { // V -> LDS transposed
    const int jr = tid >> 4, d0 = (tid & 15) * 4;
#pragma unroll
    for (int p = 0; p < 16; ++p) {
      const int j = p * 32 + jr;
      bf16x4 v = *(const bf16x4*)&base[(size_t)j * 3072 + 2048 + h * 64 + d0];
      Vt[(d0 + 0) * 520 + j] = v[0];
      Vt[(d0 + 1) * 520 + j] = v[1];
      Vt[(d0 + 2) * 520 + j] = v[2];
      Vt[(d0 + 3) * 520 + j] = v[3];
    }
  }
  bf16x8 qf[2];
  {
    const int qr = i0g + (lane & 15);
#pragma unroll
    for (int t = 0; t < 2; ++t)
      qf[t] = *(const bf16x8*)&base[(size_t)qr * 3072 + h * 64 + t * 32 + (lane >> 4) * 8];
  }
  __syncthreads();

  // S = Q K^T : each wave 16 rows x 512 cols (32 n-tiles, 2 k-steps of 32)
  f32x4 S[32];
#pragma unroll
  for (int nt = 0; nt < 32; ++nt) {
    const bf16* kb = &Ks[(nt * 16 + (lane & 15)) * 72 + (lane >> 4) * 8];
    f32x4 c = {};
    c = __builtin_amdgcn_mfma_f32_16x16x32_bf16(qf[0], *(const bf16x8*)kb, c, 0, 0, 0);
    c = __builtin_amdgcn_mfma_f32_16x16x32_bf16(qf[1], *(const bf16x8*)(kb + 32), c, 0, 0, 0);
    S[nt] = c;
  }

  // softmax over rows (C-layout: row=(lane>>4)*4+r, col=nt*16+(lane&15))
  float mx[4] = {-1e30f, -1e30f, -1e30f, -1e30f};
#pragma unroll
  for (int nt = 0; nt < 32; ++nt)
#pragma unroll
    for (int r = 0; r < 4; ++r) {
      S[nt][r] *= 0.125f;
      mx[r] = fmaxf(mx[r], S[nt][r]);
    }
#pragma unroll
  for (int m = 1; m < 16; m <<= 1)
#pragma unroll
    for (int r = 0; r < 4; ++r) mx[r] = fmaxf(mx[r], __shfl_xor(mx[r], m));
  float sm[4] = {0.f, 0.f, 0.f, 0.f};
#pragma unroll
  for (int nt = 0; nt < 32; ++nt)
#pragma unroll
    for (int r = 0; r < 4; ++r) {
      const float e = __expf(S[nt][r] - mx[r]);
      S[nt][r] = e;
      sm[r] += e;
    }
#pragma unroll
  for (int m = 1; m < 16; m <<= 1)
#pragma unroll
    for (int r = 0; r < 4; ++r) sm[r] += __shfl_xor(sm[r], m);
  float inv[4];
#pragma unroll
  for (int r = 0; r < 4; ++r) inv[r] = 1.f / sm[r];

  // O = P V: P roundtrips per-wave LDS (C-layout -> A-layout), 8 chunks of 64
  f32x4 O[4] = {};
  for (int cch = 0; cch < 8; ++cch) {
#pragma unroll
    for (int t = 0; t < 4; ++t) {
      const int nt = cch * 4 + t;
#pragma unroll
      for (int r = 0; r < 4; ++r)
        Pl[wave][((lane >> 4) * 4 + r) * 72 + t * 16 + (lane & 15)] = (bf16)S[nt][r];
    }
#pragma unroll
    for (int ktile = 0; ktile < 2; ++ktile) {
      bf16x8 pf = *(const bf16x8*)&Pl[wave][(lane & 15) * 72 + ktile * 32 + (lane >> 4) * 8];
#pragma unroll
      for (int dt = 0; dt < 4; ++dt) {
        const bf16* vb = &Vt[(dt * 16 + (lane & 15)) * 520 + cch * 64 + ktile * 32 + (lane >> 4) * 8];
        O[dt] = __builtin_amdgcn_mfma_f32_16x16x32_bf16(pf, *(const bf16x8*)vb, O[dt], 0, 0, 0);
      }
    }
  }

#pragma unroll
  for (int dt = 0; dt < 4; ++dt)
#pragma unroll
    for (int r = 0; r < 4; ++r) {
      const int i = (lane >> 4) * 4 + r;
      const int d = dt * 16 + (lane & 15);
      o[(size_t)(b * 512 + i0g + i) * 1024 + h * 64 + d] = (bf16)(O[dt][r] * inv[r]);
    }
}

// ---------------------------------------------------------------------------
// LayerNorm: x fp32 [rows,1024], fp32 scale/bias -> bf16 out (l=0 ln1 only)
// ---------------------------------------------------------------------------
__global__ __launch_bounds__(256)
void ln_k(const float* __restrict__ x, const float* __restrict__ sc,
          const float* __restrict__ bi, bf16* __restrict__ out)
{
  const int row = blockIdx.x, tid = threadIdx.x;
  f32x4 a = *(const f32x4*)&x[(size_t)row * 1024 + tid * 4];
  float s  = a[0] + a[1] + a[2] + a[3];
  float s2 = a[0]*a[0] + a[1]*a[1] + a[2]*a[2] + a[3]*a[3];
#pragma unroll
  for (int m = 32; m >= 1; m >>= 1) {
    s  += __shfl_xor(s, m);
    s2 += __shfl_xor(s2, m);
  }
  __shared__ float red[8];
  if ((tid & 63) == 0) { red[tid >> 6] = s; red[4 + (tid >> 6)] = s2; }
  __syncthreads();
  s  = red[0] + red[1] + red[2] + red[3];
  s2 = red[4] + red[5] + red[6] + red[7];
  const float mean = s * (1.f / 1024.f);
  const float var  = s2 * (1.f / 1024.f) - mean * mean;
  const float rs   = rsqrtf(var + 1e-5f);
  bf16x4 ov;
#pragma unroll
  for (int i = 0; i < 4; ++i) {
    const int c = tid * 4 + i;
    ov[i] = (bf16)((a[i] - mean) * rs * sc[c] + bi[c]);
  }
  *(bf16x4*)&out[(size_t)row * 1024 + tid * 4] = ov;
}

// ---------------------------------------------------------------------------
extern "C" void kernel_launch(void* const* d_in, const int* in_sizes, int n_in,
                              void* d_out, int out_size, void* d_ws, size_t ws_size,
                              hipStream_t stream)
{
  const float* x_in = (const float*)d_in[0];
  const float* ln1s = (const float*)d_in[1];
  const float* ln1b = (const float*)d_in[2];
  const float* wqkv = (const float*)d_in[3];
  const float* wout = (const float*)d_in[4];
  const float* bout = (const float*)d_in[5];
  const float* ln2s = (const float*)d_in[6];
  const float* ln2b = (const float*)d_in[7];
  const float* w1   = (const float*)d_in[8];
  const float* b1   = (const float*)d_in[9];
  const float* w2   = (const float*)d_in[10];
  const float* b2   = (const float*)d_in[11];

  char* ws = (char*)d_ws;
  const size_t MB = 1 << 20;
  float* xf   = (float*)(ws);              // 8 MiB fp32 residual stream
  bf16* act   = (bf16*)(ws + 8   * MB);    // 4 MiB: ln out / attn out
  bf16* qg    = (bf16*)(ws + 12  * MB);    // 16 MiB: qkv (12) then gelu (16)
  bf16* qkvT  = (bf16*)(ws + 28  * MB);    // 36 MiB [6][3072,1024]
  bf16* woutT = (bf16*)(ws + 64  * MB);    // 12 MiB [6][1024,1024]
  bf16* w1T   = (bf16*)(ws + 76  * MB);    // 48 MiB [6][4096,1024]
  bf16* w2T   = (bf16*)(ws + 124 * MB);    // 48 MiB [6][1024,4096]
  float* Pws  = (float*)(ws + 172 * MB);   // 32 MiB [4][2048,1024] fp32 partials

  // transpose-convert all layers' weights to bf16 [N,K]
  convT_k<<<dim3(16, 48, 6), 256, 0, stream>>>(wqkv, qkvT, 1024, 3072);
  convT_k<<<dim3(16, 16, 6), 256, 0, stream>>>(wout, woutT, 1024, 1024);
  convT_k<<<dim3(16, 64, 6), 256, 0, stream>>>(w1, w1T, 1024, 4096);
  convT_k<<<dim3(64, 16, 6), 256, 0, stream>>>(w2, w2T, 4096, 1024);

  for (int l = 0; l < 6; ++l) {
    const float* xres = (l == 0) ? x_in : xf;  // residual-stream input
    if (l == 0)  // ln1 for l>0 is fused into the previous layer's ff2 reduce
      ln_k<<<2048, 256, 0, stream>>>(x_in, ln1s, ln1b, act);
    gemm4r_k<0><<<dim3(16, 12, 1), 512, 0, stream>>>(
        act, qkvT + (size_t)l * 3072 * 1024, nullptr, qg, nullptr,
        2048, 3072, 1024, 1024);
    attn_k<<<dim3(64, 4), 512, 0, stream>>>(qg, act);
    // wout: split-K x4 on the ring (Kchunk=256, nk=8), reduce fuses
    // bias + residual + ln2 -> xf (fp32 stream) and act (bf16 ln2 out)
    gemm4r_k<3><<<dim3(16, 4, 4), 512, 0, stream>>>(
        act, woutT + (size_t)l * 1024 * 1024, nullptr, nullptr, Pws,
        2048, 1024, 1024, 256);
    red4_k<1><<<2048, 256, 0, stream>>>(
        Pws, bout + l * 1024, xres, xf,
        ln2s + l * 1024, ln2b + l * 1024, act, 2048, 1024);
    gemm4r_k<2><<<dim3(16, 16, 1), 512, 0, stream>>>(
        act, w1T + (size_t)l * 4096 * 1024, b1 + l * 4096, qg, nullptr,
        2048, 4096, 1024, 1024);
    // ff2: split-K x4 on the ring, reduce fuses bias + residual (+ next ln1)
    gemm4r_k<3><<<dim3(16, 4, 4), 512, 0, stream>>>(
        qg, w2T + (size_t)l * 1024 * 4096, nullptr, nullptr, Pws,
        2048, 1024, 4096, 1024);
    if (l < 5) {
      red4_k<1><<<2048, 256, 0, stream>>>(
          Pws, b2 + l * 1024, xf, xf,
          ln1s + (l + 1) * 1024, ln1b + (l + 1) * 1024, act, 2048, 1024);
    } else {
      red4_k<0><<<2048, 256, 0, stream>>>(
          Pws, b2 + l * 1024, xf, (float*)d_out,
          nullptr, nullptr, nullptr, 2048, 1024);
    }
  }
}